// Round 1
// baseline (540.257 us; speedup 1.0000x reference)
//
#include <hip/hip_runtime.h>
#include <hip/hip_bf16.h>

typedef unsigned short u16;
typedef unsigned int u32;
typedef u16 u16x4 __attribute__((ext_vector_type(4)));
typedef u16 u16x8 __attribute__((ext_vector_type(8)));
typedef short bf16x8 __attribute__((ext_vector_type(8)));
typedef float f32x4 __attribute__((ext_vector_type(4)));

// N=2, L=2048, E=1024, H=16, D=64
#define LSEQ 2048
#define EMB  1024
#define NH   32      // N*H

__device__ __forceinline__ u16 f2bf(float f) {
    union { float f; u32 u; } x; x.f = f;
    u32 u = x.u;
    return (u16)((u + 0x7FFFu + ((u >> 16) & 1u)) >> 16);
}

// -----------------------------------------------------------------------
// GEMM: C[m,n] = sum_k A[m,k] * W[n,k] + bias[n]
// M=4096, N=1024, K=1024.  A row-major (f32 or bf16), W row-major f32.
// MODE 0: out bf16 [N,H,L,D]   (Q,K heads layout)
// MODE 1: out bf16 [N,H,D,L]   (V transposed for PV MFMA B-operand)
// MODE 2: out f32  [M,E]       (final output)
// -----------------------------------------------------------------------
template<int MODE, bool A_F32>
__global__ __launch_bounds__(256) void proj_gemm(
    const void* __restrict__ Aptr, const float* __restrict__ W,
    const float* __restrict__ bias, void* __restrict__ Out)
{
    __shared__ u16 Alds[128][72];   // 72 = 64 + 8 pad; row stride 144B (16B aligned)
    __shared__ u16 Blds[128][72];

    const int tid  = threadIdx.x;
    const int lane = tid & 63;
    const int w    = tid >> 6;
    const int m0   = blockIdx.y * 128;
    const int n0   = blockIdx.x * 128;
    const int wrow = (w >> 1) * 64;
    const int wcol = (w & 1) * 64;
    const int lr   = lane & 15;
    const int lg   = lane >> 4;

    f32x4 acc[4][4] = {};

    for (int k0 = 0; k0 < 1024; k0 += 64) {
        // ---- stage A tile (128 x 64) ----
        if (A_F32) {
            const float* A = (const float*)Aptr;
            #pragma unroll
            for (int it = 0; it < 8; ++it) {
                int f = it * 256 + tid;          // float4 id 0..2047
                int row = f >> 4, cv = f & 15;
                float4 a = *(const float4*)(A + (m0 + row) * 1024 + k0 + cv * 4);
                u16x4 p;
                p[0] = f2bf(a.x); p[1] = f2bf(a.y);
                p[2] = f2bf(a.z); p[3] = f2bf(a.w);
                *(u16x4*)&Alds[row][cv * 4] = p;
            }
        } else {
            const u16* A = (const u16*)Aptr;
            #pragma unroll
            for (int it = 0; it < 4; ++it) {
                int f = it * 256 + tid;          // u16x8 id 0..1023
                int row = f >> 3, cv = f & 7;
                u16x8 v = *(const u16x8*)(A + (m0 + row) * 1024 + k0 + cv * 8);
                *(u16x8*)&Alds[row][cv * 8] = v;
            }
        }
        // ---- stage B tile: W rows n0..n0+128 (f32 -> bf16) ----
        {
            #pragma unroll
            for (int it = 0; it < 8; ++it) {
                int f = it * 256 + tid;
                int row = f >> 4, cv = f & 15;
                float4 a = *(const float4*)(W + (n0 + row) * 1024 + k0 + cv * 4);
                u16x4 p;
                p[0] = f2bf(a.x); p[1] = f2bf(a.y);
                p[2] = f2bf(a.z); p[3] = f2bf(a.w);
                *(u16x4*)&Blds[row][cv * 4] = p;
            }
        }
        __syncthreads();

        #pragma unroll
        for (int ks = 0; ks < 2; ++ks) {
            const int lk = lg * 8 + ks * 32;
            bf16x8 af[4], bfr[4];
            #pragma unroll
            for (int i = 0; i < 4; ++i)
                af[i] = *(const bf16x8*)&Alds[wrow + i * 16 + lr][lk];
            #pragma unroll
            for (int j = 0; j < 4; ++j)
                bfr[j] = *(const bf16x8*)&Blds[wcol + j * 16 + lr][lk];
            #pragma unroll
            for (int i = 0; i < 4; ++i)
                #pragma unroll
                for (int j = 0; j < 4; ++j)
                    acc[i][j] = __builtin_amdgcn_mfma_f32_16x16x32_bf16(
                        af[i], bfr[j], acc[i][j], 0, 0, 0);
        }
        __syncthreads();
    }

    // ---- epilogue ----
    #pragma unroll
    for (int j = 0; j < 4; ++j) {
        const int nn = n0 + wcol + j * 16 + lr;
        const float bj = bias[nn];
        #pragma unroll
        for (int i = 0; i < 4; ++i) {
            #pragma unroll
            for (int r = 0; r < 4; ++r) {
                const int m = m0 + wrow + i * 16 + lg * 4 + r;
                const float v = acc[i][j][r] + bj;
                if (MODE == 0) {
                    const int n = m >> 11, l = m & 2047;
                    const int h = nn >> 6, d = nn & 63;
                    ((u16*)Out)[(((n * 16 + h) * 2048) + l) * 64 + d] = f2bf(v);
                } else if (MODE == 1) {
                    const int n = m >> 11, l = m & 2047;
                    const int h = nn >> 6, d = nn & 63;
                    ((u16*)Out)[(((n * 16 + h) * 64) + d) * 2048 + l] = f2bf(v);
                } else {
                    ((float*)Out)[(size_t)m * 1024 + nn] = v;
                }
            }
        }
    }
}

// -----------------------------------------------------------------------
// Flash attention: one block = 64 q rows of one (n,h); 4 waves x 16 rows.
// Qh,Kh: bf16 [NH][L][64]; Vt: bf16 [NH][64][L]; Oout: bf16 [N,L,E].
// -----------------------------------------------------------------------
__global__ __launch_bounds__(256) void flash_attn(
    const u16* __restrict__ Qh, const u16* __restrict__ Kh,
    const u16* __restrict__ Vt, u16* __restrict__ Oout)
{
    const int tid  = threadIdx.x;
    const int lane = tid & 63;
    const int w    = tid >> 6;
    const int nh   = blockIdx.y;
    const int q0   = blockIdx.x * 64 + w * 16;
    const int lr   = lane & 15;
    const int lg   = lane >> 4;

    const u16* Qb = Qh + (size_t)nh * LSEQ * 64;
    const u16* Kb = Kh + (size_t)nh * LSEQ * 64;
    const u16* Vb = Vt + (size_t)nh * 64 * LSEQ;

    __shared__ u16 Plds[4][16][72];

    // Q fragments (A operand): lane holds Q[q0+lr][lg*8..+8] per 32-k-slice
    bf16x8 aq[2];
    aq[0] = *(const bf16x8*)(Qb + (size_t)(q0 + lr) * 64 + lg * 8);
    aq[1] = *(const bf16x8*)(Qb + (size_t)(q0 + lr) * 64 + 32 + lg * 8);

    float m_run[4], l_run[4];
    f32x4 Oacc[4] = {};
    #pragma unroll
    for (int r = 0; r < 4; ++r) { m_run[r] = -INFINITY; l_run[r] = 0.f; }

    for (int s0 = 0; s0 < LSEQ; s0 += 64) {
        // ---- S = (Q K^T) / 8 ----
        f32x4 S[4] = {};
        #pragma unroll
        for (int ct = 0; ct < 4; ++ct) {
            #pragma unroll
            for (int ks = 0; ks < 2; ++ks) {
                bf16x8 kb = *(const bf16x8*)(Kb +
                    (size_t)(s0 + ct * 16 + lr) * 64 + ks * 32 + lg * 8);
                S[ct] = __builtin_amdgcn_mfma_f32_16x16x32_bf16(
                    aq[ks], kb, S[ct], 0, 0, 0);
            }
        }
        #pragma unroll
        for (int ct = 0; ct < 4; ++ct)
            #pragma unroll
            for (int r = 0; r < 4; ++r)
                S[ct][r] *= 0.125f;

        // ---- online softmax stats ----
        float m_new[4], sf[4];
        #pragma unroll
        for (int r = 0; r < 4; ++r) {
            float tm = fmaxf(fmaxf(S[0][r], S[1][r]), fmaxf(S[2][r], S[3][r]));
            #pragma unroll
            for (int mk = 1; mk <= 8; mk <<= 1)
                tm = fmaxf(tm, __shfl_xor(tm, mk, 64));
            m_new[r] = fmaxf(m_run[r], tm);
            sf[r] = __expf(m_run[r] - m_new[r]);
        }

        float rs[4] = {0.f, 0.f, 0.f, 0.f};
        #pragma unroll
        for (int ct = 0; ct < 4; ++ct) {
            #pragma unroll
            for (int r = 0; r < 4; ++r) {
                float p = __expf(S[ct][r] - m_new[r]);
                rs[r] += p;
                Plds[w][lg * 4 + r][ct * 16 + lr] = f2bf(p);  // transpose to row-major
            }
        }
        #pragma unroll
        for (int r = 0; r < 4; ++r) {
            float s = rs[r];
            #pragma unroll
            for (int mk = 1; mk <= 8; mk <<= 1)
                s += __shfl_xor(s, mk, 64);
            l_run[r] = l_run[r] * sf[r] + s;
            m_run[r] = m_new[r];
        }
        #pragma unroll
        for (int dt = 0; dt < 4; ++dt)
            #pragma unroll
            for (int r = 0; r < 4; ++r)
                Oacc[dt][r] *= sf[r];

        __syncthreads();   // P writes -> P reads (uniform trip count across waves)

        // ---- O += P V ----
        #pragma unroll
        for (int ks = 0; ks < 2; ++ks) {
            bf16x8 pa = *(const bf16x8*)&Plds[w][lr][ks * 32 + lg * 8];
            #pragma unroll
            for (int dt = 0; dt < 4; ++dt) {
                bf16x8 vb = *(const bf16x8*)(Vb +
                    (size_t)(dt * 16 + lr) * LSEQ + s0 + ks * 32 + lg * 8);
                Oacc[dt] = __builtin_amdgcn_mfma_f32_16x16x32_bf16(
                    pa, vb, Oacc[dt], 0, 0, 0);
            }
        }
        __syncthreads();   // before next iteration overwrites Plds
    }

    // ---- epilogue: attn_out bf16 [N, L, H*D] ----
    const int n = nh >> 4, h = nh & 15;
    #pragma unroll
    for (int dt = 0; dt < 4; ++dt) {
        #pragma unroll
        for (int r = 0; r < 4; ++r) {
            float o = Oacc[dt][r] / l_run[r];
            int q = q0 + lg * 4 + r;
            Oout[((size_t)(n * LSEQ + q)) * 1024 + h * 64 + dt * 16 + lr] = f2bf(o);
        }
    }
}

extern "C" void kernel_launch(void* const* d_in, const int* in_sizes, int n_in,
                              void* d_out, int out_size, void* d_ws, size_t ws_size,
                              hipStream_t stream) {
    const float* q  = (const float*)d_in[0];
    const float* k  = (const float*)d_in[1];
    const float* v  = (const float*)d_in[2];
    const float* Wq = (const float*)d_in[3];
    const float* bq = (const float*)d_in[4];
    const float* Wk = (const float*)d_in[5];
    const float* bk = (const float*)d_in[6];
    const float* Wv = (const float*)d_in[7];
    const float* bv = (const float*)d_in[8];
    const float* Wo = (const float*)d_in[9];
    const float* bo = (const float*)d_in[10];
    float* out = (float*)d_out;

    u16* ws = (u16*)d_ws;
    u16* Qh = ws;                          // 4M u16 = 8MB
    u16* Kh = ws + (size_t)4 * 1024 * 1024;
    u16* Vt = ws + (size_t)8 * 1024 * 1024;
    u16* Ao = ws + (size_t)12 * 1024 * 1024;

    dim3 gg(8, 32), bb(256);
    proj_gemm<0, true><<<gg, bb, 0, stream>>>(q, Wq, bq, Qh);
    proj_gemm<0, true><<<gg, bb, 0, stream>>>(k, Wk, bk, Kh);
    proj_gemm<1, true><<<gg, bb, 0, stream>>>(v, Wv, bv, Vt);
    flash_attn<<<dim3(LSEQ / 64, NH), bb, 0, stream>>>(Qh, Kh, Vt, Ao);
    proj_gemm<2, false><<<gg, bb, 0, stream>>>(Ao, Wo, bo, out);
}

// Round 4
// 355.269 us; speedup vs baseline: 1.5207x; 1.5207x over previous
//
#include <hip/hip_runtime.h>
#include <hip/hip_bf16.h>

typedef unsigned short u16;
typedef unsigned int u32;
typedef u16 u16x4 __attribute__((ext_vector_type(4)));
typedef u16 u16x8 __attribute__((ext_vector_type(8)));
typedef short bf16x8 __attribute__((ext_vector_type(8)));
typedef float f32x4 __attribute__((ext_vector_type(4)));

// N=2, L=2048, E=1024, H=16, D=64
#define LSEQ 2048
#define EMB  1024
#define NH   32      // N*H

__device__ __forceinline__ u16 f2bf(float f) {
    union { float f; u32 u; } x; x.f = f;
    u32 u = x.u;
    return (u16)((u + 0x7FFFu + ((u >> 16) & 1u)) >> 16);
}

// -----------------------------------------------------------------------
// GEMM (R1 kernel, verbatim — known-good): C[m,n] = sum_k A[m,k]*W[n,k] + b[n]
// M=4096, N=1024, K=1024.  A row-major (f32 or bf16), W row-major f32.
// MODE 0: out bf16 [N,H,L,D]; MODE 1: out bf16 [N,H,D,L]; MODE 2: out f32.
// -----------------------------------------------------------------------
template<int MODE, bool A_F32>
__global__ __launch_bounds__(256) void proj_gemm(
    const void* __restrict__ Aptr, const float* __restrict__ W,
    const float* __restrict__ bias, void* __restrict__ Out)
{
    __shared__ u16 Alds[128][72];   // 72 = 64 + 8 pad; row stride 144B (16B aligned)
    __shared__ u16 Blds[128][72];

    const int tid  = threadIdx.x;
    const int lane = tid & 63;
    const int w    = tid >> 6;
    const int m0   = blockIdx.y * 128;
    const int n0   = blockIdx.x * 128;
    const int wrow = (w >> 1) * 64;
    const int wcol = (w & 1) * 64;
    const int lr   = lane & 15;
    const int lg   = lane >> 4;

    f32x4 acc[4][4] = {};

    for (int k0 = 0; k0 < 1024; k0 += 64) {
        // ---- stage A tile (128 x 64) ----
        if (A_F32) {
            const float* A = (const float*)Aptr;
            #pragma unroll
            for (int it = 0; it < 8; ++it) {
                int f = it * 256 + tid;          // float4 id 0..2047
                int row = f >> 4, cv = f & 15;
                float4 a = *(const float4*)(A + (m0 + row) * 1024 + k0 + cv * 4);
                u16x4 p;
                p[0] = f2bf(a.x); p[1] = f2bf(a.y);
                p[2] = f2bf(a.z); p[3] = f2bf(a.w);
                *(u16x4*)&Alds[row][cv * 4] = p;
            }
        } else {
            const u16* A = (const u16*)Aptr;
            #pragma unroll
            for (int it = 0; it < 4; ++it) {
                int f = it * 256 + tid;          // u16x8 id 0..1023
                int row = f >> 3, cv = f & 7;
                u16x8 v = *(const u16x8*)(A + (m0 + row) * 1024 + k0 + cv * 8);
                *(u16x8*)&Alds[row][cv * 8] = v;
            }
        }
        // ---- stage B tile: W rows n0..n0+128 (f32 -> bf16) ----
        {
            #pragma unroll
            for (int it = 0; it < 8; ++it) {
                int f = it * 256 + tid;
                int row = f >> 4, cv = f & 15;
                float4 a = *(const float4*)(W + (n0 + row) * 1024 + k0 + cv * 4);
                u16x4 p;
                p[0] = f2bf(a.x); p[1] = f2bf(a.y);
                p[2] = f2bf(a.z); p[3] = f2bf(a.w);
                *(u16x4*)&Blds[row][cv * 4] = p;
            }
        }
        __syncthreads();

        #pragma unroll
        for (int ks = 0; ks < 2; ++ks) {
            const int lk = lg * 8 + ks * 32;
            bf16x8 af[4], bfr[4];
            #pragma unroll
            for (int i = 0; i < 4; ++i)
                af[i] = *(const bf16x8*)&Alds[wrow + i * 16 + lr][lk];
            #pragma unroll
            for (int j = 0; j < 4; ++j)
                bfr[j] = *(const bf16x8*)&Blds[wcol + j * 16 + lr][lk];
            #pragma unroll
            for (int i = 0; i < 4; ++i)
                #pragma unroll
                for (int j = 0; j < 4; ++j)
                    acc[i][j] = __builtin_amdgcn_mfma_f32_16x16x32_bf16(
                        af[i], bfr[j], acc[i][j], 0, 0, 0);
        }
        __syncthreads();
    }

    // ---- epilogue ----
    #pragma unroll
    for (int j = 0; j < 4; ++j) {
        const int nn = n0 + wcol + j * 16 + lr;
        const float bj = bias[nn];
        #pragma unroll
        for (int i = 0; i < 4; ++i) {
            #pragma unroll
            for (int r = 0; r < 4; ++r) {
                const int m = m0 + wrow + i * 16 + lg * 4 + r;
                const float v = acc[i][j][r] + bj;
                if (MODE == 0) {
                    const int n = m >> 11, l = m & 2047;
                    const int h = nn >> 6, d = nn & 63;
                    ((u16*)Out)[(((n * 16 + h) * 2048) + l) * 64 + d] = f2bf(v);
                } else if (MODE == 1) {
                    const int n = m >> 11, l = m & 2047;
                    const int h = nn >> 6, d = nn & 63;
                    ((u16*)Out)[(((n * 16 + h) * 64) + d) * 2048 + l] = f2bf(v);
                } else {
                    ((float*)Out)[(size_t)m * 1024 + nn] = v;
                }
            }
        }
    }
}

// -----------------------------------------------------------------------
// Flash attention v3: block = 128 q rows of one (n,h); 4 waves x 32 rows.
// K/V tiles (64x64 bf16) cooperatively staged to padded LDS via plain
// vectorized reg loads + ds_write (NO global_load_lds). Padded stride 72
// is at the b128 bank floor for both the staging writes and fragment
// reads. T14 async split: next tile's global loads issue right after the
// barrier and are consumed at the next iteration's ds_write, hiding
// memory latency under compute. P stays wave-private in LDS (no
// barriers). 2 barriers per kv-tile, both unconditional.
// Qh,Kh: bf16 [NH][L][64]; Vt: bf16 [NH][64][L]; Oout: bf16 [N,L,E].
// -----------------------------------------------------------------------
__global__ __launch_bounds__(256) void flash_attn3(
    const u16* __restrict__ Qh, const u16* __restrict__ Kh,
    const u16* __restrict__ Vt, u16* __restrict__ Oout)
{
    const int tid  = threadIdx.x;
    const int lane = tid & 63;
    const int w    = tid >> 6;
    const int lr   = lane & 15, lg = lane >> 4;
    const int nh   = blockIdx.y;
    const int q0   = blockIdx.x * 128;

    const u16* Qb = Qh + (size_t)nh * LSEQ * 64;
    const u16* Kb = Kh + (size_t)nh * LSEQ * 64;
    const u16* Vb = Vt + (size_t)nh * 64 * LSEQ;

    __shared__ u16 Kl[64][72];       // K tile  [s][d], padded
    __shared__ u16 Vl[64][72];       // V tile  [d][s], padded
    __shared__ u16 Pl[4][32][72];    // wave-private P, padded

    // staging coords: thread covers rows sr and sr+32, 16B each
    const int sr = tid >> 3;         // 0..31
    const int sc = (tid & 7) * 8;    // 0..56 (elems)

    // Q fragments: lane holds Q[q0 + w*32 + qs*16 + lr][ks*32 + lg*8 ..+8]
    bf16x8 aq[2][2];
    #pragma unroll
    for (int qs = 0; qs < 2; ++qs)
        #pragma unroll
        for (int ks = 0; ks < 2; ++ks)
            aq[qs][ks] = *(const bf16x8*)(Qb +
                (size_t)(q0 + w * 32 + qs * 16 + lr) * 64 + ks * 32 + lg * 8);

    float m_run[2][4], l_run[2][4];
    f32x4 Oacc[2][4] = {};
    #pragma unroll
    for (int qs = 0; qs < 2; ++qs)
        #pragma unroll
        for (int r = 0; r < 4; ++r) { m_run[qs][r] = -INFINITY; l_run[qs][r] = 0.f; }

    // prologue: load tile 0 into regs
    u16x8 ldK0 = *(const u16x8*)(Kb + (size_t)sr * 64 + sc);
    u16x8 ldK1 = *(const u16x8*)(Kb + (size_t)(sr + 32) * 64 + sc);
    u16x8 ldV0 = *(const u16x8*)(Vb + (size_t)sr * LSEQ + sc);
    u16x8 ldV1 = *(const u16x8*)(Vb + (size_t)(sr + 32) * LSEQ + sc);

    for (int t = 0; t < LSEQ / 64; ++t) {
        // ---- write staged regs to LDS ----
        *(u16x8*)&Kl[sr][sc]      = ldK0;
        *(u16x8*)&Kl[sr + 32][sc] = ldK1;
        *(u16x8*)&Vl[sr][sc]      = ldV0;
        *(u16x8*)&Vl[sr + 32][sc] = ldV1;
        __syncthreads();

        // ---- issue next tile's global loads (consumed next iteration) ----
        if (t + 1 < LSEQ / 64) {
            const int s0n = (t + 1) * 64;
            ldK0 = *(const u16x8*)(Kb + (size_t)(s0n + sr) * 64 + sc);
            ldK1 = *(const u16x8*)(Kb + (size_t)(s0n + sr + 32) * 64 + sc);
            ldV0 = *(const u16x8*)(Vb + (size_t)sr * LSEQ + s0n + sc);
            ldV1 = *(const u16x8*)(Vb + (size_t)(sr + 32) * LSEQ + s0n + sc);
        }

        // ---- S = (Q K^T) / 8 ----
        f32x4 S[2][4] = {};
        #pragma unroll
        for (int ks = 0; ks < 2; ++ks) {
            #pragma unroll
            for (int ct = 0; ct < 4; ++ct) {
                bf16x8 kb = *(const bf16x8*)&Kl[ct * 16 + lr][ks * 32 + lg * 8];
                S[0][ct] = __builtin_amdgcn_mfma_f32_16x16x32_bf16(
                    aq[0][ks], kb, S[0][ct], 0, 0, 0);
                S[1][ct] = __builtin_amdgcn_mfma_f32_16x16x32_bf16(
                    aq[1][ks], kb, S[1][ct], 0, 0, 0);
            }
        }
        #pragma unroll
        for (int qs = 0; qs < 2; ++qs)
            #pragma unroll
            for (int ct = 0; ct < 4; ++ct)
                #pragma unroll
                for (int r = 0; r < 4; ++r)
                    S[qs][ct][r] *= 0.125f;

        // ---- online softmax (wave-private, no barriers) ----
        #pragma unroll
        for (int qs = 0; qs < 2; ++qs) {
            float m_new[4], sf[4], rs[4];
            #pragma unroll
            for (int r = 0; r < 4; ++r) {
                float tm = fmaxf(fmaxf(S[qs][0][r], S[qs][1][r]),
                                 fmaxf(S[qs][2][r], S[qs][3][r]));
                #pragma unroll
                for (int mk = 1; mk <= 8; mk <<= 1)
                    tm = fmaxf(tm, __shfl_xor(tm, mk, 64));
                m_new[r] = fmaxf(m_run[qs][r], tm);
                sf[r] = __expf(m_run[qs][r] - m_new[r]);
                m_run[qs][r] = m_new[r];
                rs[r] = 0.f;
            }
            #pragma unroll
            for (int ct = 0; ct < 4; ++ct)
                #pragma unroll
                for (int r = 0; r < 4; ++r) {
                    float p = __expf(S[qs][ct][r] - m_new[r]);
                    rs[r] += p;
                    Pl[w][qs * 16 + lg * 4 + r][ct * 16 + lr] = f2bf(p);
                }
            #pragma unroll
            for (int r = 0; r < 4; ++r) {
                float s = rs[r];
                #pragma unroll
                for (int mk = 1; mk <= 8; mk <<= 1)
                    s += __shfl_xor(s, mk, 64);
                l_run[qs][r] = l_run[qs][r] * sf[r] + s;
            }
            #pragma unroll
            for (int dt = 0; dt < 4; ++dt)
                #pragma unroll
                for (int r = 0; r < 4; ++r)
                    Oacc[qs][dt][r] *= sf[r];
        }

        // ---- O += P V ----
        #pragma unroll
        for (int ks = 0; ks < 2; ++ks) {
            bf16x8 pa0 = *(const bf16x8*)&Pl[w][lr][ks * 32 + lg * 8];
            bf16x8 pa1 = *(const bf16x8*)&Pl[w][16 + lr][ks * 32 + lg * 8];
            #pragma unroll
            for (int dt = 0; dt < 4; ++dt) {
                bf16x8 vb = *(const bf16x8*)&Vl[dt * 16 + lr][ks * 32 + lg * 8];
                Oacc[0][dt] = __builtin_amdgcn_mfma_f32_16x16x32_bf16(
                    pa0, vb, Oacc[0][dt], 0, 0, 0);
                Oacc[1][dt] = __builtin_amdgcn_mfma_f32_16x16x32_bf16(
                    pa1, vb, Oacc[1][dt], 0, 0, 0);
            }
        }
        __syncthreads();   // all waves done with Kl/Vl before next overwrite
    }

    // ---- epilogue: attn_out bf16 [N, L, H*D] ----
    const int n = nh >> 4, h = nh & 15;
    #pragma unroll
    for (int qs = 0; qs < 2; ++qs)
        #pragma unroll
        for (int dt = 0; dt < 4; ++dt)
            #pragma unroll
            for (int r = 0; r < 4; ++r) {
                float o = Oacc[qs][dt][r] / l_run[qs][r];
                int qq = q0 + w * 32 + qs * 16 + lg * 4 + r;
                Oout[((size_t)(n * LSEQ + qq)) * 1024 + h * 64 + dt * 16 + lr] = f2bf(o);
            }
}

extern "C" void kernel_launch(void* const* d_in, const int* in_sizes, int n_in,
                              void* d_out, int out_size, void* d_ws, size_t ws_size,
                              hipStream_t stream) {
    const float* q  = (const float*)d_in[0];
    const float* k  = (const float*)d_in[1];
    const float* v  = (const float*)d_in[2];
    const float* Wq = (const float*)d_in[3];
    const float* bq = (const float*)d_in[4];
    const float* Wk = (const float*)d_in[5];
    const float* bk = (const float*)d_in[6];
    const float* Wv = (const float*)d_in[7];
    const float* bv = (const float*)d_in[8];
    const float* Wo = (const float*)d_in[9];
    const float* bo = (const float*)d_in[10];
    float* out = (float*)d_out;

    u16* ws = (u16*)d_ws;
    u16* Qh = ws;                          // 4M u16 = 8MB each
    u16* Kh = ws + (size_t)4 * 1024 * 1024;
    u16* Vt = ws + (size_t)8 * 1024 * 1024;
    u16* Ao = ws + (size_t)12 * 1024 * 1024;

    dim3 gg(8, 32), bb(256);
    proj_gemm<0, true><<<gg, bb, 0, stream>>>(q, Wq, bq, Qh);
    proj_gemm<0, true><<<gg, bb, 0, stream>>>(k, Wk, bk, Kh);
    proj_gemm<1, true><<<gg, bb, 0, stream>>>(v, Wv, bv, Vt);
    flash_attn3<<<dim3(LSEQ / 128, NH), bb, 0, stream>>>(Qh, Kh, Vt, Ao);
    proj_gemm<2, false><<<gg, bb, 0, stream>>>(Ao, Wo, bo, out);
}

// Round 5
// 307.711 us; speedup vs baseline: 1.7557x; 1.1546x over previous
//
#include <hip/hip_runtime.h>
#include <hip/hip_bf16.h>
#include <math.h>

typedef unsigned short u16;
typedef unsigned int u32;
typedef u16 u16x4 __attribute__((ext_vector_type(4)));
typedef u16 u16x8 __attribute__((ext_vector_type(8)));
typedef short bf16x8 __attribute__((ext_vector_type(8)));
typedef float f32x4 __attribute__((ext_vector_type(4)));

// N=2, L=2048, E=1024, H=16, D=64
#define LSEQ 2048
#define NH   32

// Q-projection scale: 1/sqrt(64) * log2(e)  -> lets flash use exp2f directly
#define QSCALE 0.18033688011112042f

__device__ __forceinline__ u16 f2bf(float f) {
    __hip_bfloat16 h = __float2bfloat16(f);   // RNE; compiler can pack v_cvt_pk_bf16_f32
    union { __hip_bfloat16 h; u16 u; } c; c.h = h; return c.u;
}

// -----------------------------------------------------------------------
// f32 -> bf16 vectorized convert (grid-stride, float4 granularity)
// -----------------------------------------------------------------------
__global__ __launch_bounds__(256) void cvt_bf16(
    const float* __restrict__ src, u16* __restrict__ dst, int n4)
{
    int stride = gridDim.x * 256;
    for (int i = blockIdx.x * 256 + threadIdx.x; i < n4; i += stride) {
        float4 a = ((const float4*)src)[i];
        u16x4 p;
        p[0] = f2bf(a.x); p[1] = f2bf(a.y); p[2] = f2bf(a.z); p[3] = f2bf(a.w);
        ((u16x4*)dst)[i] = p;
    }
}

// -----------------------------------------------------------------------
// GEMM v2: C[m,n] = sum_k A[m,k]*W[n,k] + bias[n]
// A bf16 [4096][1024]; W f32 [1024][1024] (bf16-converted during staging).
// BM=128, BN=64, BK=64; grid (16,32) = 512 blocks (2/CU); 4 waves (2x2),
// wave tile 64x32. LDS rows are linear 128B; XOR slot swizzle
// (col16 ^= row&7): A staged with pre-swizzled SOURCE col + linear dest
// (write-conflict-free), B dest-swizzled u16x4 writes (bank floor).
// Double-buffered, reg-prologue, ONE barrier per K-step.
// MODE 0: bf16 [N,H,L,D]; MODE 1: bf16 [N,H,D,L]; MODE 2: f32 [M,E].
// QS!=0: scale output by QSCALE (Q projection).
// -----------------------------------------------------------------------
template<int MODE, int QS>
__global__ __launch_bounds__(256, 2) void proj_gemm2(
    const u16* __restrict__ A, const float* __restrict__ W,
    const float* __restrict__ bias, void* __restrict__ Out)
{
    __shared__ u16 Al[2][128 * 64];   // 16 KB per buf
    __shared__ u16 Bl[2][64 * 64];    //  8 KB per buf

    const int tid  = threadIdx.x;
    const int lane = tid & 63;
    const int w    = tid >> 6;
    const int lr   = lane & 15, lg = lane >> 4;
    const int t8   = tid & 7,   td8 = tid >> 3;   // A staging coords
    const int brow = tid >> 4,  bc8 = tid & 15;   // B staging coords
    const int m0   = blockIdx.y * 128;
    const int n0   = blockIdx.x * 64;
    const int wr   = (w >> 1) * 64;
    const int wc   = (w & 1) * 32;
    const int ascol = (t8 ^ (td8 & 7)) * 8;       // pre-swizzled A source col (elems)

    f32x4 acc[4][2] = {};
    u16x8 ra[4];
    float4 rb[4];

    #define LOADS(k0)                                                          \
        _Pragma("unroll")                                                      \
        for (int p_ = 0; p_ < 4; ++p_) {                                       \
            ra[p_] = *(const u16x8*)(A + (size_t)(m0 + p_ * 32 + td8) * 1024   \
                                     + (k0) + ascol);                          \
            rb[p_] = *(const float4*)(W + (size_t)(n0 + p_ * 16 + brow) * 1024 \
                                      + (k0) + bc8 * 4);                       \
        }
    #define WRITE(buf)                                                         \
        _Pragma("unroll")                                                      \
        for (int p_ = 0; p_ < 4; ++p_) {                                       \
            *(u16x8*)((char*)&Al[buf][0] + (p_ * 32 + td8) * 128 + t8 * 16)    \
                = ra[p_];                                                      \
            u16x4 pw_;                                                         \
            pw_[0] = f2bf(rb[p_].x); pw_[1] = f2bf(rb[p_].y);                  \
            pw_[2] = f2bf(rb[p_].z); pw_[3] = f2bf(rb[p_].w);                  \
            int row_ = p_ * 16 + brow;                                         \
            *(u16x4*)((char*)&Bl[buf][0] + row_ * 128                          \
                      + ((bc8 * 8) ^ ((row_ & 7) << 4))) = pw_;                \
        }

    LOADS(0)
    WRITE(0)
    LOADS(64)
    __syncthreads();

    for (int t = 0; t < 16; ++t) {
        const int c = t & 1;
        if (t + 1 < 16) {
            WRITE(c ^ 1)
            if (t + 2 < 16) LOADS((t + 2) * 64)
        }
        const char* Ac = (const char*)&Al[c][0];
        const char* Bc = (const char*)&Bl[c][0];
        #pragma unroll
        for (int ks = 0; ks < 2; ++ks) {
            const int co = ((ks * 4 + lg) * 16) ^ ((lr & 7) << 4);
            bf16x8 af[4], bfr[2];
            #pragma unroll
            for (int i = 0; i < 4; ++i)
                af[i] = *(const bf16x8*)(Ac + (wr + i * 16 + lr) * 128 + co);
            #pragma unroll
            for (int j = 0; j < 2; ++j)
                bfr[j] = *(const bf16x8*)(Bc + (wc + j * 16 + lr) * 128 + co);
            #pragma unroll
            for (int i = 0; i < 4; ++i)
                #pragma unroll
                for (int j = 0; j < 2; ++j)
                    acc[i][j] = __builtin_amdgcn_mfma_f32_16x16x32_bf16(
                        af[i], bfr[j], acc[i][j], 0, 0, 0);
        }
        __syncthreads();
    }

    // epilogue
    #pragma unroll
    for (int j = 0; j < 2; ++j) {
        const int nn = n0 + wc + j * 16 + lr;
        const float bj = bias[nn];
        #pragma unroll
        for (int i = 0; i < 4; ++i) {
            #pragma unroll
            for (int r = 0; r < 4; ++r) {
                const int m = m0 + wr + i * 16 + lg * 4 + r;
                float vv = acc[i][j][r] + bj;
                if (QS) vv *= QSCALE;
                if (MODE == 0) {
                    const int n = m >> 11, l = m & 2047;
                    const int h = nn >> 6, d = nn & 63;
                    ((u16*)Out)[(((size_t)(n * 16 + h) * 2048) + l) * 64 + d] = f2bf(vv);
                } else if (MODE == 1) {
                    const int n = m >> 11, l = m & 2047;
                    const int h = nn >> 6, d = nn & 63;
                    ((u16*)Out)[(((size_t)(n * 16 + h) * 64) + d) * 2048 + l] = f2bf(vv);
                } else {
                    ((float*)Out)[(size_t)m * 1024 + nn] = vv;
                }
            }
        }
    }
    #undef LOADS
    #undef WRITE
}

// -----------------------------------------------------------------------
// Flash attention v4: block = 128 q rows of one (n,h); 4 waves x 32 rows.
// K/V tiles in double-buffered swizzled LDS (linear 128B rows, source-
// swizzled staging via plain loads + ds_write); ONE barrier per kv-tile.
// Softmax in exp2 domain (Q pre-scaled by 1/8*log2e in projection).
// P in wave-private swizzled LDS. Qh,Kh: bf16 [NH][L][64];
// Vt: bf16 [NH][64][L]; Oout: bf16 [N,L,E].
// -----------------------------------------------------------------------
__global__ __launch_bounds__(256, 2) void flash_attn4(
    const u16* __restrict__ Qh, const u16* __restrict__ Kh,
    const u16* __restrict__ Vt, u16* __restrict__ Oout)
{
    const int tid  = threadIdx.x;
    const int lane = tid & 63;
    const int w    = tid >> 6;
    const int lr   = lane & 15, lg = lane >> 4;
    const int t8   = tid & 7,   td8 = tid >> 3;
    const int nh   = blockIdx.y;
    const int q0   = blockIdx.x * 128;
    const int scol = (t8 ^ (td8 & 7)) * 8;   // pre-swizzled source col (elems)

    const u16* Qb = Qh + (size_t)nh * LSEQ * 64;
    const u16* Kb = Kh + (size_t)nh * LSEQ * 64;
    const u16* Vb = Vt + (size_t)nh * 64 * LSEQ;

    __shared__ u16 Kl[2][64 * 64];   // [s][d] swizzled, 8 KB per buf
    __shared__ u16 Vl[2][64 * 64];   // [d][s] swizzled, 8 KB per buf
    __shared__ u16 Pl[4][32 * 64];   // wave-private, swizzled, 4 KB per wave

    // Q fragments (already scaled by QSCALE)
    bf16x8 aq[2][2];
    #pragma unroll
    for (int qs = 0; qs < 2; ++qs)
        #pragma unroll
        for (int ks = 0; ks < 2; ++ks)
            aq[qs][ks] = *(const bf16x8*)(Qb +
                (size_t)(q0 + w * 32 + qs * 16 + lr) * 64 + ks * 32 + lg * 8);

    float m_run[2][4], l_run[2][4];
    f32x4 Oacc[2][4] = {};
    #pragma unroll
    for (int qs = 0; qs < 2; ++qs)
        #pragma unroll
        for (int r = 0; r < 4; ++r) { m_run[qs][r] = -INFINITY; l_run[qs][r] = 0.f; }

    u16x8 ldK0, ldK1, ldV0, ldV1;
    #define LOADS(s0)                                                          \
        ldK0 = *(const u16x8*)(Kb + (size_t)((s0) + td8) * 64 + scol);         \
        ldK1 = *(const u16x8*)(Kb + (size_t)((s0) + td8 + 32) * 64 + scol);    \
        ldV0 = *(const u16x8*)(Vb + (size_t)td8 * LSEQ + (s0) + scol);         \
        ldV1 = *(const u16x8*)(Vb + (size_t)(td8 + 32) * LSEQ + (s0) + scol);
    #define WRITE(buf)                                                         \
        *(u16x8*)((char*)&Kl[buf][0] + td8 * 128 + t8 * 16)        = ldK0;     \
        *(u16x8*)((char*)&Kl[buf][0] + (td8 + 32) * 128 + t8 * 16) = ldK1;     \
        *(u16x8*)((char*)&Vl[buf][0] + td8 * 128 + t8 * 16)        = ldV0;     \
        *(u16x8*)((char*)&Vl[buf][0] + (td8 + 32) * 128 + t8 * 16) = ldV1;

    LOADS(0)
    WRITE(0)
    LOADS(64)
    __syncthreads();

    for (int t = 0; t < LSEQ / 64; ++t) {
        const int c = t & 1;
        if (t + 1 < LSEQ / 64) {
            WRITE(c ^ 1)
            if (t + 2 < LSEQ / 64) LOADS((t + 2) * 64)
        }
        const char* Kc = (const char*)&Kl[c][0];
        const char* Vc = (const char*)&Vl[c][0];
        char* Pw = (char*)&Pl[w][0];

        // ---- S = Q K^T  (exp2 domain) ----
        f32x4 S[2][4] = {};
        #pragma unroll
        for (int ks = 0; ks < 2; ++ks) {
            const int co = ((ks * 4 + lg) * 16) ^ ((lr & 7) << 4);
            #pragma unroll
            for (int ct = 0; ct < 4; ++ct) {
                bf16x8 kb = *(const bf16x8*)(Kc + (ct * 16 + lr) * 128 + co);
                S[0][ct] = __builtin_amdgcn_mfma_f32_16x16x32_bf16(
                    aq[0][ks], kb, S[0][ct], 0, 0, 0);
                S[1][ct] = __builtin_amdgcn_mfma_f32_16x16x32_bf16(
                    aq[1][ks], kb, S[1][ct], 0, 0, 0);
            }
        }

        // ---- online softmax (wave-private) ----
        #pragma unroll
        for (int qs = 0; qs < 2; ++qs) {
            float m_new[4], sf[4], rs[4];
            #pragma unroll
            for (int r = 0; r < 4; ++r) {
                float tm = fmaxf(fmaxf(S[qs][0][r], S[qs][1][r]),
                                 fmaxf(S[qs][2][r], S[qs][3][r]));
                #pragma unroll
                for (int mk = 1; mk <= 8; mk <<= 1)
                    tm = fmaxf(tm, __shfl_xor(tm, mk, 64));
                m_new[r] = fmaxf(m_run[qs][r], tm);
                sf[r] = exp2f(m_run[qs][r] - m_new[r]);
                m_run[qs][r] = m_new[r];
                rs[r] = 0.f;
            }
            #pragma unroll
            for (int ct = 0; ct < 4; ++ct)
                #pragma unroll
                for (int r = 0; r < 4; ++r) {
                    float p = exp2f(S[qs][ct][r] - m_new[r]);
                    rs[r] += p;
                    int pr = qs * 16 + lg * 4 + r;
                    *(u16*)(Pw + pr * 128 +
                            (((ct * 16 + lr) * 2) ^ ((pr & 7) << 4))) = f2bf(p);
                }
            #pragma unroll
            for (int r = 0; r < 4; ++r) {
                float s = rs[r];
                #pragma unroll
                for (int mk = 1; mk <= 8; mk <<= 1)
                    s += __shfl_xor(s, mk, 64);
                l_run[qs][r] = l_run[qs][r] * sf[r] + s;
            }
            #pragma unroll
            for (int dt = 0; dt < 4; ++dt)
                #pragma unroll
                for (int r = 0; r < 4; ++r)
                    Oacc[qs][dt][r] *= sf[r];
        }

        // ---- O += P V ----
        #pragma unroll
        for (int ks = 0; ks < 2; ++ks) {
            const int co = ((ks * 4 + lg) * 16) ^ ((lr & 7) << 4);
            bf16x8 pa0 = *(const bf16x8*)(Pw + lr * 128 + co);
            bf16x8 pa1 = *(const bf16x8*)(Pw + (16 + lr) * 128 + co);
            #pragma unroll
            for (int dt = 0; dt < 4; ++dt) {
                bf16x8 vb = *(const bf16x8*)(Vc + (dt * 16 + lr) * 128 + co);
                Oacc[0][dt] = __builtin_amdgcn_mfma_f32_16x16x32_bf16(
                    pa0, vb, Oacc[0][dt], 0, 0, 0);
                Oacc[1][dt] = __builtin_amdgcn_mfma_f32_16x16x32_bf16(
                    pa1, vb, Oacc[1][dt], 0, 0, 0);
            }
        }
        __syncthreads();
    }
    #undef LOADS
    #undef WRITE

    // ---- epilogue: attn_out bf16 [N, L, H*D] ----
    const int n = nh >> 4, h = nh & 15;
    #pragma unroll
    for (int qs = 0; qs < 2; ++qs)
        #pragma unroll
        for (int dt = 0; dt < 4; ++dt)
            #pragma unroll
            for (int r = 0; r < 4; ++r) {
                float o = Oacc[qs][dt][r] / l_run[qs][r];
                int qq = q0 + w * 32 + qs * 16 + lg * 4 + r;
                Oout[((size_t)(n * LSEQ + qq)) * 1024 + h * 64 + dt * 16 + lr] = f2bf(o);
            }
}

extern "C" void kernel_launch(void* const* d_in, const int* in_sizes, int n_in,
                              void* d_out, int out_size, void* d_ws, size_t ws_size,
                              hipStream_t stream) {
    const float* q  = (const float*)d_in[0];
    const float* k  = (const float*)d_in[1];
    const float* v  = (const float*)d_in[2];
    const float* Wq = (const float*)d_in[3];
    const float* bq = (const float*)d_in[4];
    const float* Wk = (const float*)d_in[5];
    const float* bk = (const float*)d_in[6];
    const float* Wv = (const float*)d_in[7];
    const float* bv = (const float*)d_in[8];
    const float* Wo = (const float*)d_in[9];
    const float* bo = (const float*)d_in[10];

    // ws (u16 units), 32 MB total, slot-rotated:
    //   S1=Qh, S2=Kh, S3=Vt, S4=scratch (bf16 input, then attn-out)
    u16* ws = (u16*)d_ws;
    u16* Qh = ws;
    u16* Kh = ws + (size_t)4 * 1024 * 1024;
    u16* Vt = ws + (size_t)8 * 1024 * 1024;
    u16* S4 = ws + (size_t)12 * 1024 * 1024;

    const int n4 = (2 * LSEQ * 1024) / 4;
    dim3 cg(2048), cb(256);
    dim3 gg(16, 32), gb(256);   // GEMM: x = N/64, y = M/128

    cvt_bf16<<<cg, cb, 0, stream>>>(q, S4, n4);
    proj_gemm2<0, 1><<<gg, gb, 0, stream>>>(S4, Wq, bq, Qh);
    cvt_bf16<<<cg, cb, 0, stream>>>(k, S4, n4);
    proj_gemm2<0, 0><<<gg, gb, 0, stream>>>(S4, Wk, bk, Kh);
    cvt_bf16<<<cg, cb, 0, stream>>>(v, S4, n4);
    proj_gemm2<1, 0><<<gg, gb, 0, stream>>>(S4, Wv, bv, Vt);
    flash_attn4<<<dim3(LSEQ / 128, NH), gb, 0, stream>>>(Qh, Kh, Vt, S4);
    proj_gemm2<2, 0><<<gg, gb, 0, stream>>>(S4, Wo, bo, (float*)d_out);
}